// Round 4
// baseline (150.156 us; speedup 1.0000x reference)
//
#include <hip/hip_runtime.h>

#define GRIDN 256
#define BPA 16                      // bins per axis (16 cells each)
#define NBINS (BPA * BPA * BPA)     // 4096
#define CAP 768                     // slots per bin (mean 593, sigma 24 -> mu+7.2sigma)
#define CURSOR_STRIDE 16            // one cursor per 64B line
#define REG 20                      // staged region edge: cells [x0-2, x0+17]
#define REGV (REG * REG * REG)      // 8000 floats = 32 KB

// ---------- shared helpers ----------

__device__ __forceinline__ int cell_guess(float c) {
    float t = (c + 0.64f) * 200.0f;
    int i = (int)t;
    return min(max(i, 0), GRIDN - 1);
}

// exact jnp.searchsorted(p, c, side='left') + clip semantics
__device__ __forceinline__ void dim_interp(float c, const float* __restrict__ p,
                                           int& il, int& ir, float& dl, float& dr) {
    const float SCALE = 0.005f;
    const float OFFSET = -0.64f;
    float t = (c - OFFSET) * (1.0f / SCALE);
    int i = (int)ceilf(t);
    i = min(max(i, 0), GRIDN - 1);
    while (i < GRIDN - 1 && p[i] < c) ++i;
    while (i > 0 && p[i - 1] >= c) --i;
    ir = i;
    il = max(i - 1, 0);
    dl = fmaxf(c - p[il], 0.0f);
    dr = fmaxf(p[ir] - c, 0.0f);
    if (dl == 0.0f && dr == 0.0f) { dl = 1.0f; dr = 1.0f; }
}

__device__ __forceinline__ float interp_weights_combine(
        float dxl, float dxr, float dyl, float dyr, float dzl, float dzr,
        float v000, float v001, float v010, float v011,
        float v100, float v101, float v110, float v111) {
    float num =
        v000 * (dxr * dyr * dzr) +
        v001 * (dxr * dyr * dzl) +
        v010 * (dxr * dyl * dzr) +
        v011 * (dxr * dyl * dzl) +
        v100 * (dxl * dyr * dzr) +
        v101 * (dxl * dyr * dzl) +
        v110 * (dxl * dyl * dzr) +
        v111 * (dxl * dyl * dzl);
    float den = (dxl + dxr) * (dyl + dyr) * (dzl + dzr);
    return num / den;
}

__device__ __forceinline__ float interp_point(float cx, float cy, float cz,
                                              const float* __restrict__ values,
                                              const float* __restrict__ px,
                                              const float* __restrict__ py,
                                              const float* __restrict__ pz) {
    int ixl, ixr, iyl, iyr, izl, izr;
    float dxl, dxr, dyl, dyr, dzl, dzr;
    dim_interp(cx, px, ixl, ixr, dxl, dxr);
    dim_interp(cy, py, iyl, iyr, dyl, dyr);
    dim_interp(cz, pz, izl, izr, dzl, dzr);
    int bxl = ixl << 16, bxr = ixr << 16;
    int byl = iyl << 8,  byr = iyr << 8;
    return interp_weights_combine(dxl, dxr, dyl, dyr, dzl, dzr,
        values[bxl + byl + izl], values[bxl + byl + izr],
        values[bxl + byr + izl], values[bxl + byr + izr],
        values[bxr + byl + izl], values[bxr + byl + izr],
        values[bxr + byr + izl], values[bxr + byr + izr]);
}

__device__ __forceinline__ int bin_of(float cx, float cy, float cz) {
    int bx = cell_guess(cx) >> 4;
    int by = cell_guess(cy) >> 4;
    int bz = cell_guess(cz) >> 4;
    return (bx * BPA + by) * BPA + bz;
}

// ---------- K0: init padded cursors ----------

__global__ void init_cursors(unsigned* __restrict__ cursor) {
    int t = blockIdx.x * blockDim.x + threadIdx.x;
    if (t < NBINS) cursor[t * CURSOR_STRIDE] = (unsigned)(t * CAP);
}

// ---------- K1: block-aggregated bin scatter ----------

#define K1_THREADS 1024
#define K1_PTS 16384

__global__ __launch_bounds__(K1_THREADS) void bin_scatter3(
        const float* __restrict__ x, int K,
        unsigned* __restrict__ cursor,
        float4* __restrict__ records,
        int* __restrict__ inv,
        const float* __restrict__ values,
        const float* __restrict__ px,
        const float* __restrict__ py,
        const float* __restrict__ pz,
        float* __restrict__ out) {
    __shared__ unsigned cnt[NBINS];   // counts, then per-bin next-slot cursors

    int base = blockIdx.x * K1_PTS;
    int end = min(base + K1_PTS, K);

    for (int t = threadIdx.x; t < NBINS; t += K1_THREADS) cnt[t] = 0;
    __syncthreads();

    // phase A: count
    for (int i = base + threadIdx.x; i < end; i += K1_THREADS) {
        int b = bin_of(x[3 * i], x[3 * i + 1], x[3 * i + 2]);
        atomicAdd(&cnt[b], 1u);
    }
    __syncthreads();

    // phase B: one aggregated global atomic per occupied bin; cnt[t] becomes slot cursor
    for (int t = threadIdx.x; t < NBINS; t += K1_THREADS) {
        unsigned c = cnt[t];
        cnt[t] = c ? atomicAdd(&cursor[t * CURSOR_STRIDE], c) : 0u;
    }
    __syncthreads();

    // phase C: write records into reserved runs; inv coalesced by i
    for (int i = base + threadIdx.x; i < end; i += K1_THREADS) {
        float cx = x[3 * i], cy = x[3 * i + 1], cz = x[3 * i + 2];
        int b = bin_of(cx, cy, cz);
        unsigned s = atomicAdd(&cnt[b], 1u);
        if (s < (unsigned)((b + 1) * CAP)) {
            records[s] = make_float4(cx, cy, cz, 0.0f);
            inv[i] = (int)s;
        } else {
            inv[i] = -1;   // bin overflow (statistically never): compute inline
            out[i] = interp_point(cx, cy, cz, values, px, py, pz);
        }
    }
}

// ---------- K2: one block per bin, LDS-staged value region ----------

__global__ __launch_bounds__(256) void interp_lds(
        const float4* __restrict__ records,
        const unsigned* __restrict__ cursor,
        const float* __restrict__ values,
        const float* __restrict__ px,
        const float* __restrict__ py,
        const float* __restrict__ pz,
        float* __restrict__ res) {
    __shared__ float sval[REG][REG][REG];

    // bijective XCD swizzle (NBINS % 8 == 0): consecutive bins -> same XCD L2
    int nb = gridDim.x;
    int b = blockIdx.x;
    int q = nb >> 3;
    int bin = (b & 7) * q + (b >> 3);

    unsigned binstart = (unsigned)bin * CAP;
    unsigned segend = min(cursor[bin * CURSOR_STRIDE], binstart + CAP);
    int npts = (int)(segend - binstart);
    if (npts <= 0) return;

    int bz = bin & (BPA - 1);
    int by = (bin >> 4) & (BPA - 1);
    int bx = bin >> 8;
    int rx0 = bx * 16 - 2, ry0 = by * 16 - 2, rz0 = bz * 16 - 2;

    // stage region (clamped at volume edges)
    for (int lin = threadIdx.x; lin < REGV; lin += 256) {
        int u = lin / (REG * REG);
        int rem = lin - u * (REG * REG);
        int v = rem / REG;
        int w = rem - v * REG;
        int gx = min(max(rx0 + u, 0), GRIDN - 1);
        int gy = min(max(ry0 + v, 0), GRIDN - 1);
        int gz = min(max(rz0 + w, 0), GRIDN - 1);
        sval[u][v][w] = values[(gx << 16) | (gy << 8) | gz];
    }
    __syncthreads();

    for (int pt = threadIdx.x; pt < npts; pt += 256) {
        float4 rec = records[binstart + pt];
        int ixl, ixr, iyl, iyr, izl, izr;
        float dxl, dxr, dyl, dyr, dzl, dzr;
        dim_interp(rec.x, px, ixl, ixr, dxl, dxr);
        dim_interp(rec.y, py, iyl, iyr, dyl, dyr);
        dim_interp(rec.z, pz, izl, izr, dzl, dzr);

        int lxl = ixl - rx0, lxr = ixr - rx0;
        int lyl = iyl - ry0, lyr = iyr - ry0;
        int lzl = izl - rz0, lzr = izr - rz0;

        float r;
        if ((unsigned)lxl < REG && (unsigned)lxr < REG &&
            (unsigned)lyl < REG && (unsigned)lyr < REG &&
            (unsigned)lzl < REG && (unsigned)lzr < REG) {
            r = interp_weights_combine(dxl, dxr, dyl, dyr, dzl, dzr,
                sval[lxl][lyl][lzl], sval[lxl][lyl][lzr],
                sval[lxl][lyr][lzl], sval[lxl][lyr][lzr],
                sval[lxr][lyl][lzl], sval[lxr][lyl][lzr],
                sval[lxr][lyr][lzl], sval[lxr][lyr][lzr]);
        } else {
            // searchsorted wandered past the guard band (should never happen)
            r = interp_point(rec.x, rec.y, rec.z, values, px, py, pz);
        }
        res[binstart + pt] = r;
    }
}

// ---------- K3: unscatter results to original order ----------

__global__ void unscatter(const int* __restrict__ inv,
                          const float* __restrict__ res,
                          float* __restrict__ out, int K) {
    int i = blockIdx.x * blockDim.x + threadIdx.x;
    if (i >= K) return;
    int s = inv[i];
    if (s >= 0) out[i] = res[s];
}

// ---------- fallback: direct (round-1) kernel ----------

__global__ void trilerp_direct(const float* __restrict__ x,
                               const float* __restrict__ values,
                               const float* __restrict__ px,
                               const float* __restrict__ py,
                               const float* __restrict__ pz,
                               float* __restrict__ out, int K) {
    int i = blockIdx.x * blockDim.x + threadIdx.x;
    if (i >= K) return;
    out[i] = interp_point(x[3 * i], x[3 * i + 1], x[3 * i + 2], values, px, py, pz);
}

extern "C" void kernel_launch(void* const* d_in, const int* in_sizes, int n_in,
                              void* d_out, int out_size, void* d_ws, size_t ws_size,
                              hipStream_t stream) {
    const float* x      = (const float*)d_in[0];
    const float* values = (const float*)d_in[1];
    const float* px     = (const float*)d_in[2];
    const float* py     = (const float*)d_in[3];
    const float* pz     = (const float*)d_in[4];
    float* out = (float*)d_out;

    int K = in_sizes[0] / 3;

    size_t cursor_bytes  = (size_t)NBINS * CURSOR_STRIDE * 4;   // 256 KB
    size_t records_bytes = (size_t)NBINS * CAP * 16;            // 50.3 MB
    size_t inv_bytes     = (size_t)K * 4;                       // 8 MB
    size_t res_bytes     = (size_t)NBINS * CAP * 4;             // 12.6 MB
    size_t need = cursor_bytes + records_bytes + inv_bytes + res_bytes;

    if (ws_size < need) {
        int grid = (K + 255) / 256;
        trilerp_direct<<<grid, 256, 0, stream>>>(x, values, px, py, pz, out, K);
        return;
    }

    unsigned* cursor = (unsigned*)d_ws;
    float4* records  = (float4*)((char*)d_ws + cursor_bytes);
    int* inv         = (int*)((char*)d_ws + cursor_bytes + records_bytes);
    float* res       = (float*)((char*)d_ws + cursor_bytes + records_bytes + inv_bytes);

    init_cursors<<<(NBINS + 255) / 256, 256, 0, stream>>>(cursor);

    int nblk1 = (K + K1_PTS - 1) / K1_PTS;
    bin_scatter3<<<nblk1, K1_THREADS, 0, stream>>>(x, K, cursor, records, inv,
                                                   values, px, py, pz, out);

    interp_lds<<<NBINS, 256, 0, stream>>>(records, cursor, values, px, py, pz, res);

    int nblk3 = (K + 255) / 256;
    unscatter<<<nblk3, 256, 0, stream>>>(inv, res, out, K);
}

// Round 5
// 121.617 us; speedup vs baseline: 1.2347x; 1.2347x over previous
//
#include <hip/hip_runtime.h>

#define GRIDN 256
#define BPA 8                     // coarse bins per axis (32 cells each)
#define NBINS (BPA * BPA * BPA)   // 512
#define CAP 6144                  // slots per bin (mean ~3900, generous)
#define CURSOR_STRIDE 16          // one cursor per 64B line
#define FBINS 64                  // fine bins per coarse bin: 8x8 in (x,y), z coarse

// ---------- shared helpers ----------

__device__ __forceinline__ int cell_guess(float c) {
    float t = (c + 0.64f) * 200.0f;
    int i = (int)t;
    return min(max(i, 0), GRIDN - 1);
}

// exact jnp.searchsorted(p, c, side='left') + clip semantics
__device__ __forceinline__ void dim_interp(float c, const float* __restrict__ p,
                                           int& il, int& ir, float& dl, float& dr) {
    const float SCALE = 0.005f;
    const float OFFSET = -0.64f;
    float t = (c - OFFSET) * (1.0f / SCALE);
    int i = (int)ceilf(t);
    i = min(max(i, 0), GRIDN - 1);
    while (i < GRIDN - 1 && p[i] < c) ++i;
    while (i > 0 && p[i - 1] >= c) --i;
    ir = i;
    il = max(i - 1, 0);
    dl = fmaxf(c - p[il], 0.0f);
    dr = fmaxf(p[ir] - c, 0.0f);
    if (dl == 0.0f && dr == 0.0f) { dl = 1.0f; dr = 1.0f; }
}

__device__ __forceinline__ float interp_weights_combine(
        float dxl, float dxr, float dyl, float dyr, float dzl, float dzr,
        float v000, float v001, float v010, float v011,
        float v100, float v101, float v110, float v111) {
    float num =
        v000 * (dxr * dyr * dzr) +
        v001 * (dxr * dyr * dzl) +
        v010 * (dxr * dyl * dzr) +
        v011 * (dxr * dyl * dzl) +
        v100 * (dxl * dyr * dzr) +
        v101 * (dxl * dyr * dzl) +
        v110 * (dxl * dyl * dzr) +
        v111 * (dxl * dyl * dzl);
    float den = (dxl + dxr) * (dyl + dyr) * (dzl + dzr);
    return num / den;
}

__device__ __forceinline__ float interp_point_ax(float cx, float cy, float cz,
                                                 const float* __restrict__ values,
                                                 const float* __restrict__ ax,
                                                 const float* __restrict__ ay,
                                                 const float* __restrict__ az) {
    int ixl, ixr, iyl, iyr, izl, izr;
    float dxl, dxr, dyl, dyr, dzl, dzr;
    dim_interp(cx, ax, ixl, ixr, dxl, dxr);
    dim_interp(cy, ay, iyl, iyr, dyl, dyr);
    dim_interp(cz, az, izl, izr, dzl, dzr);
    int bxl = ixl << 16, bxr = ixr << 16;
    int byl = iyl << 8,  byr = iyr << 8;
    return interp_weights_combine(dxl, dxr, dyl, dyr, dzl, dzr,
        values[bxl + byl + izl], values[bxl + byl + izr],
        values[bxl + byr + izl], values[bxl + byr + izr],
        values[bxr + byl + izl], values[bxr + byl + izr],
        values[bxr + byr + izl], values[bxr + byr + izr]);
}

__device__ __forceinline__ int bin_of(float cx, float cy, float cz) {
    int bx = cell_guess(cx) >> 5;
    int by = cell_guess(cy) >> 5;
    int bz = cell_guess(cz) >> 5;
    return (bx * BPA + by) * BPA + bz;
}

// ---------- K0: init padded cursors ----------

__global__ void init_cursors(unsigned* __restrict__ cursor) {
    int t = blockIdx.x * blockDim.x + threadIdx.x;
    if (t < NBINS) cursor[t * CURSOR_STRIDE] = (unsigned)(t * CAP);
}

// ---------- K1: block-aggregated coarse bin scatter (proven in R3) ----------

__global__ __launch_bounds__(1024) void bin_scatter2(
        const float* __restrict__ x, int K,
        unsigned* __restrict__ cursor,
        float4* __restrict__ records,
        int* __restrict__ inv,
        const float* __restrict__ values,
        const float* __restrict__ px,
        const float* __restrict__ py,
        const float* __restrict__ pz,
        float* __restrict__ out) {
    __shared__ unsigned cnt[NBINS];
    __shared__ unsigned slotcur[NBINS];

    int base = blockIdx.x * 4096;
    int end = min(base + 4096, K);

    for (int t = threadIdx.x; t < NBINS; t += 1024) cnt[t] = 0;
    __syncthreads();

    for (int i = base + threadIdx.x; i < end; i += 1024) {
        int b = bin_of(x[3 * i], x[3 * i + 1], x[3 * i + 2]);
        atomicAdd(&cnt[b], 1u);
    }
    __syncthreads();

    for (int t = threadIdx.x; t < NBINS; t += 1024)
        slotcur[t] = cnt[t] ? atomicAdd(&cursor[t * CURSOR_STRIDE], cnt[t]) : 0u;
    __syncthreads();

    for (int i = base + threadIdx.x; i < end; i += 1024) {
        float cx = x[3 * i], cy = x[3 * i + 1], cz = x[3 * i + 2];
        int b = bin_of(cx, cy, cz);
        unsigned s = atomicAdd(&slotcur[b], 1u);
        if (s < (unsigned)((b + 1) * CAP)) {
            records[s] = make_float4(cx, cy, cz, 0.0f);
            inv[i] = (int)s;
        } else {
            inv[i] = -1;   // overflow (statistically never): compute inline
            out[i] = interp_point_ax(cx, cy, cz, values, px, py, pz);
        }
    }
}

// ---------- K2: per-bin fine counting sort in LDS, then gather ----------

__global__ __launch_bounds__(256) void interp_fsorted(
        const float4* __restrict__ records,
        const unsigned* __restrict__ cursor,
        const float* __restrict__ values,
        const float* __restrict__ px,
        const float* __restrict__ py,
        const float* __restrict__ pz,
        float* __restrict__ res) {
    __shared__ float sax[3 * GRIDN];              // axes: 3 KB
    __shared__ unsigned hist[FBINS];              // 256 B
    __shared__ unsigned short order[CAP];         // 12 KB
    __shared__ unsigned char keys[CAP];           // 6 KB

    // bijective XCD swizzle: consecutive bins on the same XCD
    int nb = gridDim.x;               // 512 (divisible by 8)
    int b = blockIdx.x;
    int q = nb >> 3;
    int bin = (b & 7) * q + (b >> 3);

    // stage axes into LDS (removes scattered L1 loads in searchsorted fixup)
    for (int t = threadIdx.x; t < GRIDN; t += 256) {
        sax[t] = px[t];
        sax[GRIDN + t] = py[t];
        sax[2 * GRIDN + t] = pz[t];
    }
    if (threadIdx.x < FBINS) hist[threadIdx.x] = 0;
    __syncthreads();

    unsigned binstart = (unsigned)bin * CAP;
    unsigned segend = min(cursor[bin * CURSOR_STRIDE], binstart + CAP);
    int npts = (int)(segend - binstart);
    if (npts <= 0) return;

    int cbx = (bin >> 6) * 32;
    int cby = ((bin >> 3) & 7) * 32;

    // phase 1: fine keys (4x4xZ cells -> 8x8 bins in (x,y)) + histogram
    for (int pt = threadIdx.x; pt < npts; pt += 256) {
        float4 rec = records[binstart + pt];
        int fx = (cell_guess(rec.x) - cbx) >> 2;
        int fy = (cell_guess(rec.y) - cby) >> 2;
        fx = min(max(fx, 0), 7);
        fy = min(max(fy, 0), 7);
        int k = (fx << 3) | fy;
        keys[pt] = (unsigned char)k;
        atomicAdd(&hist[k], 1u);
    }
    __syncthreads();

    // phase 2: exclusive scan of 64 counts in the first wave
    if (threadIdx.x < 64) {
        unsigned v = hist[threadIdx.x];
        unsigned s = v;
        for (int off = 1; off < 64; off <<= 1) {
            unsigned t = __shfl_up(s, off, 64);
            if (threadIdx.x >= off) s += t;
        }
        hist[threadIdx.x] = s - v;   // exclusive prefix
    }
    __syncthreads();

    // phase 3: scatter point indices into fine-sorted order
    for (int pt = threadIdx.x; pt < npts; pt += 256) {
        unsigned slot = atomicAdd(&hist[keys[pt]], 1u);
        order[slot] = (unsigned short)pt;
    }
    __syncthreads();

    // phase 4: process in fine-sorted order — a wave's 64 pts share a ~16x16-cell
    // footprint whose corner lines (along z) mostly coincide
    for (int pt = threadIdx.x; pt < npts; pt += 256) {
        int j = order[pt];
        float4 rec = records[binstart + j];
        float r = interp_point_ax(rec.x, rec.y, rec.z, values,
                                  &sax[0], &sax[GRIDN], &sax[2 * GRIDN]);
        res[binstart + j] = r;
    }
}

// ---------- K3: unscatter results to original order ----------

__global__ void unscatter(const int* __restrict__ inv,
                          const float* __restrict__ res,
                          float* __restrict__ out, int K) {
    int i = blockIdx.x * blockDim.x + threadIdx.x;
    if (i >= K) return;
    int s = inv[i];
    if (s >= 0) out[i] = res[s];
}

// ---------- fallback: direct (round-1) kernel ----------

__global__ void trilerp_direct(const float* __restrict__ x,
                               const float* __restrict__ values,
                               const float* __restrict__ px,
                               const float* __restrict__ py,
                               const float* __restrict__ pz,
                               float* __restrict__ out, int K) {
    int i = blockIdx.x * blockDim.x + threadIdx.x;
    if (i >= K) return;
    out[i] = interp_point_ax(x[3 * i], x[3 * i + 1], x[3 * i + 2],
                             values, px, py, pz);
}

extern "C" void kernel_launch(void* const* d_in, const int* in_sizes, int n_in,
                              void* d_out, int out_size, void* d_ws, size_t ws_size,
                              hipStream_t stream) {
    const float* x      = (const float*)d_in[0];
    const float* values = (const float*)d_in[1];
    const float* px     = (const float*)d_in[2];
    const float* py     = (const float*)d_in[3];
    const float* pz     = (const float*)d_in[4];
    float* out = (float*)d_out;

    int K = in_sizes[0] / 3;

    size_t cursor_bytes  = (size_t)NBINS * CURSOR_STRIDE * 4;   // 32 KB
    size_t records_bytes = (size_t)NBINS * CAP * 16;            // 50.3 MB
    size_t inv_bytes     = (size_t)K * 4;                       // 8 MB
    size_t res_bytes     = (size_t)NBINS * CAP * 4;             // 12.6 MB
    size_t need = cursor_bytes + records_bytes + inv_bytes + res_bytes;

    if (ws_size < need) {
        int grid = (K + 255) / 256;
        trilerp_direct<<<grid, 256, 0, stream>>>(x, values, px, py, pz, out, K);
        return;
    }

    unsigned* cursor = (unsigned*)d_ws;
    float4* records  = (float4*)((char*)d_ws + cursor_bytes);
    int* inv         = (int*)((char*)d_ws + cursor_bytes + records_bytes);
    float* res       = (float*)((char*)d_ws + cursor_bytes + records_bytes + inv_bytes);

    init_cursors<<<2, 256, 0, stream>>>(cursor);

    int nblk1 = (K + 4095) / 4096;
    bin_scatter2<<<nblk1, 1024, 0, stream>>>(x, K, cursor, records, inv,
                                             values, px, py, pz, out);

    interp_fsorted<<<NBINS, 256, 0, stream>>>(records, cursor, values, px, py, pz, res);

    int nblk3 = (K + 255) / 256;
    unscatter<<<nblk3, 256, 0, stream>>>(inv, res, out, K);
}

// Round 6
// 109.478 us; speedup vs baseline: 1.3716x; 1.1109x over previous
//
#include <hip/hip_runtime.h>

#define GRIDN 256
#define BPA 8                     // coarse bins per axis (32 cells each)
#define NBINS (BPA * BPA * BPA)   // 512
#define CAP 5120                  // slots per coarse bin (interior mean 4740, sigma ~69)
#define CURSOR_STRIDE 16          // one cursor per 64B line
#define FKEYS 512                 // fine bins per coarse bin: 8x8x8 of 4x4x4 cells

// ---------- shared helpers ----------

__device__ __forceinline__ int cell_guess(float c) {
    float t = (c + 0.64f) * 200.0f;
    int i = (int)t;
    return min(max(i, 0), GRIDN - 1);
}

// exact jnp.searchsorted(p, c, side='left') + clip semantics
__device__ __forceinline__ void dim_interp(float c, const float* __restrict__ p,
                                           int& il, int& ir, float& dl, float& dr) {
    const float SCALE = 0.005f;
    const float OFFSET = -0.64f;
    float t = (c - OFFSET) * (1.0f / SCALE);
    int i = (int)ceilf(t);
    i = min(max(i, 0), GRIDN - 1);
    while (i < GRIDN - 1 && p[i] < c) ++i;
    while (i > 0 && p[i - 1] >= c) --i;
    ir = i;
    il = max(i - 1, 0);
    dl = fmaxf(c - p[il], 0.0f);
    dr = fmaxf(p[ir] - c, 0.0f);
    if (dl == 0.0f && dr == 0.0f) { dl = 1.0f; dr = 1.0f; }
}

// full interp, 8 scalar gathers (used only on rare fallback paths)
__device__ __forceinline__ float interp_point_ax(float cx, float cy, float cz,
                                                 const float* __restrict__ values,
                                                 const float* __restrict__ ax,
                                                 const float* __restrict__ ay,
                                                 const float* __restrict__ az) {
    int ixl, ixr, iyl, iyr, izl, izr;
    float dxl, dxr, dyl, dyr, dzl, dzr;
    dim_interp(cx, ax, ixl, ixr, dxl, dxr);
    dim_interp(cy, ay, iyl, iyr, dyl, dyr);
    dim_interp(cz, az, izl, izr, dzl, dzr);
    int bxl = ixl << 16, bxr = ixr << 16;
    int byl = iyl << 8,  byr = iyr << 8;
    float num =
        values[bxl + byl + izl] * (dxr * dyr * dzr) +
        values[bxl + byl + izr] * (dxr * dyr * dzl) +
        values[bxl + byr + izl] * (dxr * dyl * dzr) +
        values[bxl + byr + izr] * (dxr * dyl * dzl) +
        values[bxr + byl + izl] * (dxl * dyr * dzr) +
        values[bxr + byl + izr] * (dxl * dyr * dzl) +
        values[bxr + byr + izl] * (dxl * dyl * dzr) +
        values[bxr + byr + izr] * (dxl * dyl * dzl);
    float den = (dxl + dxr) * (dyl + dyr) * (dzl + dzr);
    return num / den;
}

// interp with z-pair dwordx2 gathers (4 memory ops instead of 8).
// Relies on il == max(ir-1,0) => ir in {il, il+1}; when ir==il (only at ir==0)
// the float2 at [0,1] is in-bounds and we select .x for both corners.
__device__ __forceinline__ float interp_zpair(float cx, float cy, float cz,
                                              const float* __restrict__ values,
                                              const float* __restrict__ sax) {
    int ixl, ixr, iyl, iyr, izl, izr;
    float dxl, dxr, dyl, dyr, dzl, dzr;
    dim_interp(cx, sax,             ixl, ixr, dxl, dxr);
    dim_interp(cy, sax + GRIDN,     iyl, iyr, dyl, dyr);
    dim_interp(cz, sax + 2 * GRIDN, izl, izr, dzl, dzr);

    int bxl = ixl << 16, bxr = ixr << 16;
    int byl = iyl << 8,  byr = iyr << 8;

    float2 vll, vlr, vrl, vrr;
    __builtin_memcpy(&vll, &values[bxl + byl + izl], 8);
    __builtin_memcpy(&vlr, &values[bxl + byr + izl], 8);
    __builtin_memcpy(&vrl, &values[bxr + byl + izl], 8);
    __builtin_memcpy(&vrr, &values[bxr + byr + izl], 8);

    bool zsame = (izr == izl);
    float zll = vll.x, zlr = zsame ? vll.x : vll.y;
    float yll = vlr.x, ylr = zsame ? vlr.x : vlr.y;
    float xll = vrl.x, xlr = zsame ? vrl.x : vrl.y;
    float wll = vrr.x, wlr = zsame ? vrr.x : vrr.y;

    // z-index left gets weight dzr, z-index right gets dzl (reference mapping)
    float num =
        (dxr * dyr) * (zll * dzr + zlr * dzl) +
        (dxr * dyl) * (yll * dzr + ylr * dzl) +
        (dxl * dyr) * (xll * dzr + xlr * dzl) +
        (dxl * dyl) * (wll * dzr + wlr * dzl);
    float den = (dxl + dxr) * (dyl + dyr) * (dzl + dzr);
    return num / den;
}

// ---------- K0: init padded cursors ----------

__global__ void init_cursors(unsigned* __restrict__ cursor) {
    int t = blockIdx.x * blockDim.x + threadIdx.x;
    if (t < NBINS) cursor[t * CURSOR_STRIDE] = (unsigned)(t * CAP);
}

// ---------- K1: block-aggregated coarse bin scatter + fine-key emission ----------

__global__ __launch_bounds__(1024) void bin_scatter2(
        const float* __restrict__ x, int K,
        unsigned* __restrict__ cursor,
        float4* __restrict__ records,
        unsigned short* __restrict__ finekey,
        int* __restrict__ inv,
        const float* __restrict__ values,
        const float* __restrict__ px,
        const float* __restrict__ py,
        const float* __restrict__ pz,
        float* __restrict__ out) {
    __shared__ unsigned cnt[NBINS];
    __shared__ unsigned slotcur[NBINS];

    int base = blockIdx.x * 4096;
    int end = min(base + 4096, K);

    for (int t = threadIdx.x; t < NBINS; t += 1024) cnt[t] = 0;
    __syncthreads();

    for (int i = base + threadIdx.x; i < end; i += 1024) {
        int cgx = cell_guess(x[3 * i]);
        int cgy = cell_guess(x[3 * i + 1]);
        int cgz = cell_guess(x[3 * i + 2]);
        int b = ((cgx >> 5) * BPA + (cgy >> 5)) * BPA + (cgz >> 5);
        atomicAdd(&cnt[b], 1u);
    }
    __syncthreads();

    for (int t = threadIdx.x; t < NBINS; t += 1024)
        slotcur[t] = cnt[t] ? atomicAdd(&cursor[t * CURSOR_STRIDE], cnt[t]) : 0u;
    __syncthreads();

    for (int i = base + threadIdx.x; i < end; i += 1024) {
        float cx = x[3 * i], cy = x[3 * i + 1], cz = x[3 * i + 2];
        int cgx = cell_guess(cx), cgy = cell_guess(cy), cgz = cell_guess(cz);
        int b = ((cgx >> 5) * BPA + (cgy >> 5)) * BPA + (cgz >> 5);
        unsigned s = atomicAdd(&slotcur[b], 1u);
        if (s < (unsigned)((b + 1) * CAP)) {
            records[s] = make_float4(cx, cy, cz, 0.0f);
            // fine key: 4x4x4-cell sub-bin, z fastest -> sorted order is z-local
            int fk = ((((cgx >> 2) & 7) << 3) | ((cgy >> 2) & 7)) << 3 | ((cgz >> 2) & 7);
            finekey[s] = (unsigned short)fk;
            inv[i] = (int)s;
        } else {
            inv[i] = -1;   // overflow (statistically never): compute inline
            out[i] = interp_point_ax(cx, cy, cz, values, px, py, pz);
        }
    }
}

// ---------- K2: per-bin 3D fine counting sort in LDS, z-paired gathers ----------

#define K2_THREADS 1024

__global__ __launch_bounds__(K2_THREADS) void interp_fsorted(
        const float4* __restrict__ records,
        const unsigned* __restrict__ cursor,
        const unsigned short* __restrict__ finekey,
        const float* __restrict__ values,
        const float* __restrict__ px,
        const float* __restrict__ py,
        const float* __restrict__ pz,
        float* __restrict__ res) {
    __shared__ float sax[3 * GRIDN];          // 3 KB
    __shared__ unsigned hist[FKEYS];          // 2 KB
    __shared__ unsigned short skeys[CAP];     // 10 KB
    __shared__ unsigned short order[CAP];     // 10 KB
    __shared__ float sres[CAP];               // 20 KB

    // bijective XCD swizzle: consecutive bins on the same XCD
    int nb = gridDim.x;               // 512, divisible by 8
    int b = blockIdx.x;
    int q = nb >> 3;
    int bin = (b & 7) * q + (b >> 3);

    for (int t = threadIdx.x; t < GRIDN; t += K2_THREADS) {
        sax[t] = px[t];
        sax[GRIDN + t] = py[t];
        sax[2 * GRIDN + t] = pz[t];
    }
    for (int t = threadIdx.x; t < FKEYS; t += K2_THREADS) hist[t] = 0;
    __syncthreads();

    unsigned binstart = (unsigned)bin * CAP;
    unsigned segend = min(cursor[bin * CURSOR_STRIDE], binstart + CAP);
    int npts = (int)(segend - binstart);
    if (npts <= 0) return;

    // phase 1: load fine keys (coalesced 2B) + histogram
    for (int pt = threadIdx.x; pt < npts; pt += K2_THREADS) {
        unsigned short k = finekey[binstart + pt];
        skeys[pt] = k;
        atomicAdd(&hist[k], 1u);
    }
    __syncthreads();

    // phase 2: exclusive scan of 512 counts (Hillis-Steele, uniform barriers)
    unsigned own = (threadIdx.x < FKEYS) ? hist[threadIdx.x] : 0u;
    for (int off = 1; off < FKEYS; off <<= 1) {
        unsigned v = 0;
        if (threadIdx.x < FKEYS && (int)threadIdx.x >= off) v = hist[threadIdx.x - off];
        __syncthreads();
        if (threadIdx.x < FKEYS) hist[threadIdx.x] += v;
        __syncthreads();
    }
    if (threadIdx.x < FKEYS) hist[threadIdx.x] -= own;   // inclusive -> exclusive
    __syncthreads();

    // phase 3: scatter point indices into fine-sorted order
    for (int pt = threadIdx.x; pt < npts; pt += K2_THREADS) {
        unsigned slot = atomicAdd(&hist[skeys[pt]], 1u);
        order[slot] = (unsigned short)pt;
    }
    __syncthreads();

    // phase 4: process in fine-sorted order; results staged scattered in LDS
    for (int pt = threadIdx.x; pt < npts; pt += K2_THREADS) {
        int j = order[pt];
        float4 rec = records[binstart + j];
        sres[j] = interp_zpair(rec.x, rec.y, rec.z, values, sax);
    }
    __syncthreads();

    // phase 5: dense coalesced writeout (kills write amplification)
    for (int pt = threadIdx.x; pt < npts; pt += K2_THREADS)
        res[binstart + pt] = sres[pt];
}

// ---------- K3: unscatter results to original order ----------

__global__ void unscatter(const int* __restrict__ inv,
                          const float* __restrict__ res,
                          float* __restrict__ out, int K) {
    int i = blockIdx.x * blockDim.x + threadIdx.x;
    if (i >= K) return;
    int s = inv[i];
    if (s >= 0) out[i] = res[s];
}

// ---------- fallback: direct (round-1) kernel ----------

__global__ void trilerp_direct(const float* __restrict__ x,
                               const float* __restrict__ values,
                               const float* __restrict__ px,
                               const float* __restrict__ py,
                               const float* __restrict__ pz,
                               float* __restrict__ out, int K) {
    int i = blockIdx.x * blockDim.x + threadIdx.x;
    if (i >= K) return;
    out[i] = interp_point_ax(x[3 * i], x[3 * i + 1], x[3 * i + 2],
                             values, px, py, pz);
}

extern "C" void kernel_launch(void* const* d_in, const int* in_sizes, int n_in,
                              void* d_out, int out_size, void* d_ws, size_t ws_size,
                              hipStream_t stream) {
    const float* x      = (const float*)d_in[0];
    const float* values = (const float*)d_in[1];
    const float* px     = (const float*)d_in[2];
    const float* py     = (const float*)d_in[3];
    const float* pz     = (const float*)d_in[4];
    float* out = (float*)d_out;

    int K = in_sizes[0] / 3;

    size_t cursor_bytes  = (size_t)NBINS * CURSOR_STRIDE * 4;   // 32 KB
    size_t records_bytes = (size_t)NBINS * CAP * 16;            // 41.9 MB
    size_t finekey_bytes = (size_t)NBINS * CAP * 2;             // 5.2 MB
    size_t inv_bytes     = (size_t)K * 4;                       // 8 MB
    size_t res_bytes     = (size_t)NBINS * CAP * 4;             // 10.5 MB
    size_t need = cursor_bytes + records_bytes + finekey_bytes + inv_bytes + res_bytes;

    if (ws_size < need) {
        int grid = (K + 255) / 256;
        trilerp_direct<<<grid, 256, 0, stream>>>(x, values, px, py, pz, out, K);
        return;
    }

    char* p = (char*)d_ws;
    unsigned* cursor        = (unsigned*)p;        p += cursor_bytes;
    float4* records         = (float4*)p;          p += records_bytes;
    unsigned short* finekey = (unsigned short*)p;  p += finekey_bytes;
    int* inv                = (int*)p;             p += inv_bytes;
    float* res              = (float*)p;

    init_cursors<<<2, 256, 0, stream>>>(cursor);

    int nblk1 = (K + 4095) / 4096;
    bin_scatter2<<<nblk1, 1024, 0, stream>>>(x, K, cursor, records, finekey, inv,
                                             values, px, py, pz, out);

    interp_fsorted<<<NBINS, K2_THREADS, 0, stream>>>(records, cursor, finekey,
                                                     values, px, py, pz, res);

    int nblk3 = (K + 255) / 256;
    unscatter<<<nblk3, 256, 0, stream>>>(inv, res, out, K);
}

// Round 7
// 107.318 us; speedup vs baseline: 1.3992x; 1.0201x over previous
//
#include <hip/hip_runtime.h>

#define GRIDN 256
#define BPA 16                    // bins per axis (16 cells each)
#define NBINS (BPA * BPA * BPA)   // 4096
#define CAP 768                   // slots per bin (interior mean 593, sigma ~24)
#define CURSOR_STRIDE 16          // one cursor per 64B line
#define FKEYS 64                  // fine bins: 4x4x4 of 4x4x4 cells, z fastest

// ---------- shared helpers ----------

__device__ __forceinline__ int cell_guess(float c) {
    float t = (c + 0.64f) * 200.0f;
    int i = (int)t;
    return min(max(i, 0), GRIDN - 1);
}

// exact jnp.searchsorted(p, c, side='left') + clip semantics
__device__ __forceinline__ void dim_interp(float c, const float* __restrict__ p,
                                           int& il, int& ir, float& dl, float& dr) {
    const float SCALE = 0.005f;
    const float OFFSET = -0.64f;
    float t = (c - OFFSET) * (1.0f / SCALE);
    int i = (int)ceilf(t);
    i = min(max(i, 0), GRIDN - 1);
    while (i < GRIDN - 1 && p[i] < c) ++i;
    while (i > 0 && p[i - 1] >= c) --i;
    ir = i;
    il = max(i - 1, 0);
    dl = fmaxf(c - p[il], 0.0f);
    dr = fmaxf(p[ir] - c, 0.0f);
    if (dl == 0.0f && dr == 0.0f) { dl = 1.0f; dr = 1.0f; }
}

// full interp, 8 scalar gathers (rare fallback paths only)
__device__ __forceinline__ float interp_point_ax(float cx, float cy, float cz,
                                                 const float* __restrict__ values,
                                                 const float* __restrict__ ax,
                                                 const float* __restrict__ ay,
                                                 const float* __restrict__ az) {
    int ixl, ixr, iyl, iyr, izl, izr;
    float dxl, dxr, dyl, dyr, dzl, dzr;
    dim_interp(cx, ax, ixl, ixr, dxl, dxr);
    dim_interp(cy, ay, iyl, iyr, dyl, dyr);
    dim_interp(cz, az, izl, izr, dzl, dzr);
    int bxl = ixl << 16, bxr = ixr << 16;
    int byl = iyl << 8,  byr = iyr << 8;
    float num =
        values[bxl + byl + izl] * (dxr * dyr * dzr) +
        values[bxl + byl + izr] * (dxr * dyr * dzl) +
        values[bxl + byr + izl] * (dxr * dyl * dzr) +
        values[bxl + byr + izr] * (dxr * dyl * dzl) +
        values[bxr + byl + izl] * (dxl * dyr * dzr) +
        values[bxr + byl + izr] * (dxl * dyr * dzl) +
        values[bxr + byr + izl] * (dxl * dyl * dzr) +
        values[bxr + byr + izr] * (dxl * dyl * dzl);
    float den = (dxl + dxr) * (dyl + dyr) * (dzl + dzr);
    return num / den;
}

// interp with z-pair dwordx2 gathers (4 memory ops). ir in {il, il+1};
// izl <= 254 so the float2 is always in-bounds; select .x when izr==izl.
__device__ __forceinline__ float interp_zpair(float cx, float cy, float cz,
                                              const float* __restrict__ values,
                                              const float* __restrict__ sax) {
    int ixl, ixr, iyl, iyr, izl, izr;
    float dxl, dxr, dyl, dyr, dzl, dzr;
    dim_interp(cx, sax,             ixl, ixr, dxl, dxr);
    dim_interp(cy, sax + GRIDN,     iyl, iyr, dyl, dyr);
    dim_interp(cz, sax + 2 * GRIDN, izl, izr, dzl, dzr);

    int bxl = ixl << 16, bxr = ixr << 16;
    int byl = iyl << 8,  byr = iyr << 8;

    float2 vll, vlr, vrl, vrr;
    __builtin_memcpy(&vll, &values[bxl + byl + izl], 8);
    __builtin_memcpy(&vlr, &values[bxl + byr + izl], 8);
    __builtin_memcpy(&vrl, &values[bxr + byl + izl], 8);
    __builtin_memcpy(&vrr, &values[bxr + byr + izl], 8);

    bool zsame = (izr == izl);
    float zll = vll.x, zlr = zsame ? vll.x : vll.y;
    float yll = vlr.x, ylr = zsame ? vlr.x : vlr.y;
    float xll = vrl.x, xlr = zsame ? vrl.x : vrl.y;
    float wll = vrr.x, wlr = zsame ? vrr.x : vrr.y;

    float num =
        (dxr * dyr) * (zll * dzr + zlr * dzl) +
        (dxr * dyl) * (yll * dzr + ylr * dzl) +
        (dxl * dyr) * (xll * dzr + xlr * dzl) +
        (dxl * dyl) * (wll * dzr + wlr * dzl);
    float den = (dxl + dxr) * (dyl + dyr) * (dzl + dzr);
    return num / den;
}

// ---------- K0: init padded cursors ----------

__global__ void init_cursors(unsigned* __restrict__ cursor) {
    int t = blockIdx.x * blockDim.x + threadIdx.x;
    if (t < NBINS) cursor[t * CURSOR_STRIDE] = (unsigned)(t * CAP);
}

// ---------- K1: block-aggregated bin scatter (R4-proven geometry) ----------

#define K1_THREADS 1024
#define K1_PTS 16384

__global__ __launch_bounds__(K1_THREADS) void bin_scatter3(
        const float* __restrict__ x, int K,
        unsigned* __restrict__ cursor,
        float4* __restrict__ records,
        int* __restrict__ inv,
        const float* __restrict__ values,
        const float* __restrict__ px,
        const float* __restrict__ py,
        const float* __restrict__ pz,
        float* __restrict__ out) {
    __shared__ unsigned cnt[NBINS];   // counts, then per-bin next-slot cursors

    int base = blockIdx.x * K1_PTS;
    int end = min(base + K1_PTS, K);

    for (int t = threadIdx.x; t < NBINS; t += K1_THREADS) cnt[t] = 0;
    __syncthreads();

    for (int i = base + threadIdx.x; i < end; i += K1_THREADS) {
        int bx = cell_guess(x[3 * i]) >> 4;
        int by = cell_guess(x[3 * i + 1]) >> 4;
        int bz = cell_guess(x[3 * i + 2]) >> 4;
        atomicAdd(&cnt[(bx * BPA + by) * BPA + bz], 1u);
    }
    __syncthreads();

    for (int t = threadIdx.x; t < NBINS; t += K1_THREADS) {
        unsigned c = cnt[t];
        cnt[t] = c ? atomicAdd(&cursor[t * CURSOR_STRIDE], c) : 0u;
    }
    __syncthreads();

    for (int i = base + threadIdx.x; i < end; i += K1_THREADS) {
        float cx = x[3 * i], cy = x[3 * i + 1], cz = x[3 * i + 2];
        int bx = cell_guess(cx) >> 4;
        int by = cell_guess(cy) >> 4;
        int bz = cell_guess(cz) >> 4;
        int b = (bx * BPA + by) * BPA + bz;
        unsigned s = atomicAdd(&cnt[b], 1u);
        if (s < (unsigned)((b + 1) * CAP)) {
            records[s] = make_float4(cx, cy, cz, 0.0f);
            inv[i] = (int)s;
        } else {
            inv[i] = -1;   // overflow (statistically never): compute inline
            out[i] = interp_point_ax(cx, cy, cz, values, px, py, pz);
        }
    }
}

// ---------- K2: one block per 16-cell bin; points in LDS; fine z-sort ----------

#define K2_THREADS 256

__global__ __launch_bounds__(K2_THREADS) void interp_fsorted2(
        const float4* __restrict__ records,
        const unsigned* __restrict__ cursor,
        const float* __restrict__ values,
        const float* __restrict__ px,
        const float* __restrict__ py,
        const float* __restrict__ pz,
        float* __restrict__ res) {
    __shared__ float sax[3 * GRIDN];          // 3 KB
    __shared__ unsigned hist[FKEYS];          // 256 B
    __shared__ unsigned char skeys[CAP];      // 768 B
    __shared__ unsigned short order[CAP];     // 1.5 KB
    __shared__ float sx[CAP], sy[CAP], sz[CAP];  // 9 KB
    __shared__ float sres[CAP];               // 3 KB

    // bijective XCD swizzle: consecutive bins (same x,y column) on one XCD
    int nb = gridDim.x;               // 4096, divisible by 8
    int b = blockIdx.x;
    int q = nb >> 3;
    int bin = (b & 7) * q + (b >> 3);

    for (int t = threadIdx.x; t < GRIDN; t += K2_THREADS) {
        sax[t] = px[t];
        sax[GRIDN + t] = py[t];
        sax[2 * GRIDN + t] = pz[t];
    }
    if (threadIdx.x < FKEYS) hist[threadIdx.x] = 0;
    __syncthreads();

    unsigned binstart = (unsigned)bin * CAP;
    unsigned segend = min(cursor[bin * CURSOR_STRIDE], binstart + CAP);
    int npts = (int)(segend - binstart);
    if (npts <= 0) return;

    int cbx = (bin >> 8) << 4;
    int cby = ((bin >> 4) & 15) << 4;
    int cbz = (bin & 15) << 4;

    // phase 1: ONE coalesced read of records -> LDS; fine key + histogram
    for (int pt = threadIdx.x; pt < npts; pt += K2_THREADS) {
        float4 rec = records[binstart + pt];
        sx[pt] = rec.x; sy[pt] = rec.y; sz[pt] = rec.z;
        int fx = (cell_guess(rec.x) - cbx) >> 2;
        int fy = (cell_guess(rec.y) - cby) >> 2;
        int fz = (cell_guess(rec.z) - cbz) >> 2;
        fx = min(max(fx, 0), 3); fy = min(max(fy, 0), 3); fz = min(max(fz, 0), 3);
        int k = ((fx << 2) | fy) << 2 | fz;    // z fastest
        skeys[pt] = (unsigned char)k;
        atomicAdd(&hist[k], 1u);
    }
    __syncthreads();

    // phase 2: exclusive scan of 64 counts (first wave)
    if (threadIdx.x < 64) {
        unsigned v = hist[threadIdx.x];
        unsigned s = v;
        for (int off = 1; off < 64; off <<= 1) {
            unsigned t = __shfl_up(s, off, 64);
            if ((int)threadIdx.x >= off) s += t;
        }
        hist[threadIdx.x] = s - v;
    }
    __syncthreads();

    // phase 3: scatter point indices into fine-sorted order
    for (int pt = threadIdx.x; pt < npts; pt += K2_THREADS) {
        unsigned slot = atomicAdd(&hist[skeys[pt]], 1u);
        order[slot] = (unsigned short)pt;
    }
    __syncthreads();

    // phase 4: process in z-sorted order; all point data from LDS;
    // gathers hit single-line z-rows (16 floats = one aligned 64B line)
    for (int pt = threadIdx.x; pt < npts; pt += K2_THREADS) {
        int j = order[pt];
        sres[j] = interp_zpair(sx[j], sy[j], sz[j], values, sax);
    }
    __syncthreads();

    // phase 5: dense coalesced writeout
    for (int pt = threadIdx.x; pt < npts; pt += K2_THREADS)
        res[binstart + pt] = sres[pt];
}

// ---------- K3: unscatter results to original order ----------

__global__ void unscatter(const int* __restrict__ inv,
                          const float* __restrict__ res,
                          float* __restrict__ out, int K) {
    int i = blockIdx.x * blockDim.x + threadIdx.x;
    if (i >= K) return;
    int s = inv[i];
    if (s >= 0) out[i] = res[s];
}

// ---------- fallback: direct (round-1) kernel ----------

__global__ void trilerp_direct(const float* __restrict__ x,
                               const float* __restrict__ values,
                               const float* __restrict__ px,
                               const float* __restrict__ py,
                               const float* __restrict__ pz,
                               float* __restrict__ out, int K) {
    int i = blockIdx.x * blockDim.x + threadIdx.x;
    if (i >= K) return;
    out[i] = interp_point_ax(x[3 * i], x[3 * i + 1], x[3 * i + 2],
                             values, px, py, pz);
}

extern "C" void kernel_launch(void* const* d_in, const int* in_sizes, int n_in,
                              void* d_out, int out_size, void* d_ws, size_t ws_size,
                              hipStream_t stream) {
    const float* x      = (const float*)d_in[0];
    const float* values = (const float*)d_in[1];
    const float* px     = (const float*)d_in[2];
    const float* py     = (const float*)d_in[3];
    const float* pz     = (const float*)d_in[4];
    float* out = (float*)d_out;

    int K = in_sizes[0] / 3;

    size_t cursor_bytes  = (size_t)NBINS * CURSOR_STRIDE * 4;   // 256 KB
    size_t records_bytes = (size_t)NBINS * CAP * 16;            // 50.3 MB
    size_t inv_bytes     = (size_t)K * 4;                       // 8 MB
    size_t res_bytes     = (size_t)NBINS * CAP * 4;             // 12.6 MB
    size_t need = cursor_bytes + records_bytes + inv_bytes + res_bytes;

    if (ws_size < need) {
        int grid = (K + 255) / 256;
        trilerp_direct<<<grid, 256, 0, stream>>>(x, values, px, py, pz, out, K);
        return;
    }

    char* p = (char*)d_ws;
    unsigned* cursor = (unsigned*)p;  p += cursor_bytes;
    float4* records  = (float4*)p;    p += records_bytes;
    int* inv         = (int*)p;       p += inv_bytes;
    float* res       = (float*)p;

    init_cursors<<<(NBINS + 255) / 256, 256, 0, stream>>>(cursor);

    int nblk1 = (K + K1_PTS - 1) / K1_PTS;
    bin_scatter3<<<nblk1, K1_THREADS, 0, stream>>>(x, K, cursor, records, inv,
                                                   values, px, py, pz, out);

    interp_fsorted2<<<NBINS, K2_THREADS, 0, stream>>>(records, cursor,
                                                      values, px, py, pz, res);

    int nblk3 = (K + 255) / 256;
    unscatter<<<nblk3, 256, 0, stream>>>(inv, res, out, K);
}

// Round 8
// 89.172 us; speedup vs baseline: 1.6839x; 1.2035x over previous
//
#include <hip/hip_runtime.h>

#define GRIDN 256
#define BPA 8                     // coarse bins per axis (32 cells each)
#define NBINS (BPA * BPA * BPA)   // 512
#define CAP 6144                  // slots per coarse bin (interior mean 4741, sigma 69)
#define CURSOR_STRIDE 16          // one cursor per 64B line
#define SUBS 8                    // K2 blocks per coarse bin
#define MAXP (CAP / SUBS)         // 768 pts per K2 block
#define FKEYS 64                  // fine keys: 4x4x4 sub-bins of 8x8x8 cells

// ---------- shared helpers ----------

__device__ __forceinline__ int cell_guess(float c) {
    float t = (c + 0.64f) * 200.0f;
    int i = (int)t;
    return min(max(i, 0), GRIDN - 1);
}

// exact jnp.searchsorted(p, c, side='left') + clip semantics
__device__ __forceinline__ void dim_interp(float c, const float* __restrict__ p,
                                           int& il, int& ir, float& dl, float& dr) {
    const float SCALE = 0.005f;
    const float OFFSET = -0.64f;
    float t = (c - OFFSET) * (1.0f / SCALE);
    int i = (int)ceilf(t);
    i = min(max(i, 0), GRIDN - 1);
    while (i < GRIDN - 1 && p[i] < c) ++i;
    while (i > 0 && p[i - 1] >= c) --i;
    ir = i;
    il = max(i - 1, 0);
    dl = fmaxf(c - p[il], 0.0f);
    dr = fmaxf(p[ir] - c, 0.0f);
    if (dl == 0.0f && dr == 0.0f) { dl = 1.0f; dr = 1.0f; }
}

// full interp, 8 scalar gathers (rare fallback paths only)
__device__ __forceinline__ float interp_point_ax(float cx, float cy, float cz,
                                                 const float* __restrict__ values,
                                                 const float* __restrict__ ax,
                                                 const float* __restrict__ ay,
                                                 const float* __restrict__ az) {
    int ixl, ixr, iyl, iyr, izl, izr;
    float dxl, dxr, dyl, dyr, dzl, dzr;
    dim_interp(cx, ax, ixl, ixr, dxl, dxr);
    dim_interp(cy, ay, iyl, iyr, dyl, dyr);
    dim_interp(cz, az, izl, izr, dzl, dzr);
    int bxl = ixl << 16, bxr = ixr << 16;
    int byl = iyl << 8,  byr = iyr << 8;
    float num =
        values[bxl + byl + izl] * (dxr * dyr * dzr) +
        values[bxl + byl + izr] * (dxr * dyr * dzl) +
        values[bxl + byr + izl] * (dxr * dyl * dzr) +
        values[bxl + byr + izr] * (dxr * dyl * dzl) +
        values[bxr + byl + izl] * (dxl * dyr * dzr) +
        values[bxr + byl + izr] * (dxl * dyr * dzl) +
        values[bxr + byr + izl] * (dxl * dyl * dzr) +
        values[bxr + byr + izr] * (dxl * dyl * dzl);
    float den = (dxl + dxr) * (dyl + dyr) * (dzl + dzr);
    return num / den;
}

// interp with z-pair dwordx2 gathers (4 memory ops). ir in {il, il+1};
// izl <= 254 so the float2 is in-bounds; select .x when izr==izl.
__device__ __forceinline__ float interp_zpair(float cx, float cy, float cz,
                                              const float* __restrict__ values,
                                              const float* __restrict__ sax) {
    int ixl, ixr, iyl, iyr, izl, izr;
    float dxl, dxr, dyl, dyr, dzl, dzr;
    dim_interp(cx, sax,             ixl, ixr, dxl, dxr);
    dim_interp(cy, sax + GRIDN,     iyl, iyr, dyl, dyr);
    dim_interp(cz, sax + 2 * GRIDN, izl, izr, dzl, dzr);

    int bxl = ixl << 16, bxr = ixr << 16;
    int byl = iyl << 8,  byr = iyr << 8;

    float2 vll, vlr, vrl, vrr;
    __builtin_memcpy(&vll, &values[bxl + byl + izl], 8);
    __builtin_memcpy(&vlr, &values[bxl + byr + izl], 8);
    __builtin_memcpy(&vrl, &values[bxr + byl + izl], 8);
    __builtin_memcpy(&vrr, &values[bxr + byr + izl], 8);

    bool zsame = (izr == izl);
    float zll = vll.x, zlr = zsame ? vll.x : vll.y;
    float yll = vlr.x, ylr = zsame ? vlr.x : vlr.y;
    float xll = vrl.x, xlr = zsame ? vrl.x : vrl.y;
    float wll = vrr.x, wlr = zsame ? vrr.x : vrr.y;

    float num =
        (dxr * dyr) * (zll * dzr + zlr * dzl) +
        (dxr * dyl) * (yll * dzr + ylr * dzl) +
        (dxl * dyr) * (xll * dzr + xlr * dzl) +
        (dxl * dyl) * (wll * dzr + wlr * dzl);
    float den = (dxl + dxr) * (dyl + dyr) * (dzl + dzr);
    return num / den;
}

// ---------- K0: init padded cursors ----------

__global__ void init_cursors(unsigned* __restrict__ cursor) {
    int t = blockIdx.x * blockDim.x + threadIdx.x;
    if (t < NBINS) cursor[t * CURSOR_STRIDE] = (unsigned)(t * CAP);
}

// ---------- K1: block-aggregated coarse bin scatter (R3-proven geometry) ----------

__global__ __launch_bounds__(1024) void bin_scatter2(
        const float* __restrict__ x, int K,
        unsigned* __restrict__ cursor,
        float4* __restrict__ records,
        int* __restrict__ inv,
        const float* __restrict__ values,
        const float* __restrict__ px,
        const float* __restrict__ py,
        const float* __restrict__ pz,
        float* __restrict__ out) {
    __shared__ unsigned cnt[NBINS];
    __shared__ unsigned slotcur[NBINS];

    int base = blockIdx.x * 4096;
    int end = min(base + 4096, K);

    for (int t = threadIdx.x; t < NBINS; t += 1024) cnt[t] = 0;
    __syncthreads();

    for (int i = base + threadIdx.x; i < end; i += 1024) {
        int bx = cell_guess(x[3 * i]) >> 5;
        int by = cell_guess(x[3 * i + 1]) >> 5;
        int bz = cell_guess(x[3 * i + 2]) >> 5;
        atomicAdd(&cnt[(bx * BPA + by) * BPA + bz], 1u);
    }
    __syncthreads();

    for (int t = threadIdx.x; t < NBINS; t += 1024)
        slotcur[t] = cnt[t] ? atomicAdd(&cursor[t * CURSOR_STRIDE], cnt[t]) : 0u;
    __syncthreads();

    for (int i = base + threadIdx.x; i < end; i += 1024) {
        float cx = x[3 * i], cy = x[3 * i + 1], cz = x[3 * i + 2];
        int bx = cell_guess(cx) >> 5;
        int by = cell_guess(cy) >> 5;
        int bz = cell_guess(cz) >> 5;
        int b = (bx * BPA + by) * BPA + bz;
        unsigned s = atomicAdd(&slotcur[b], 1u);
        if (s < (unsigned)((b + 1) * CAP)) {
            records[s] = make_float4(cx, cy, cz, 0.0f);
            inv[i] = (int)s;
        } else {
            inv[i] = -1;   // overflow (statistically never): compute inline
            out[i] = interp_point_ax(cx, cy, cz, values, px, py, pz);
        }
    }
}

// ---------- K2: 8 blocks per coarse bin; local fine z-sort in LDS ----------

#define K2_THREADS 256

__global__ __launch_bounds__(K2_THREADS) void interp_sub(
        const float4* __restrict__ records,
        const unsigned* __restrict__ cursor,
        const float* __restrict__ values,
        const float* __restrict__ px,
        const float* __restrict__ py,
        const float* __restrict__ pz,
        float* __restrict__ res) {
    __shared__ float sax[3 * GRIDN];            // 3 KB
    __shared__ unsigned hist[FKEYS];            // 256 B
    __shared__ unsigned char skeys[MAXP];       // 768 B
    __shared__ unsigned short order[MAXP];      // 1.5 KB
    __shared__ float sx[MAXP], sy[MAXP], sz[MAXP], sres[MAXP];  // 12 KB

    // bijective XCD swizzle; the 8 sub-blocks of a bin stay on one XCD
    int nb = gridDim.x;               // 4096, divisible by 8
    int b = blockIdx.x;
    int q = nb >> 3;
    int lin = (b & 7) * q + (b >> 3);
    int bin = lin >> 3;
    int sub = lin & 7;

    for (int t = threadIdx.x; t < GRIDN; t += K2_THREADS) {
        sax[t] = px[t];
        sax[GRIDN + t] = py[t];
        sax[2 * GRIDN + t] = pz[t];
    }
    if (threadIdx.x < FKEYS) hist[threadIdx.x] = 0;
    __syncthreads();

    unsigned binstart = (unsigned)bin * CAP;
    unsigned segend = min(cursor[bin * CURSOR_STRIDE], binstart + CAP);
    int npts = (int)(segend - binstart);
    if (npts <= 0) return;

    int cnt = (npts + SUBS - 1) / SUBS;      // <= MAXP
    int lo = sub * cnt;
    int hi = min(npts, lo + cnt);
    int n = hi - lo;
    if (n <= 0) return;
    unsigned base = binstart + lo;

    int cbx = (bin >> 6) << 5;
    int cby = ((bin >> 3) & 7) << 5;
    int cbz = (bin & 7) << 5;

    // phase 1: coalesced load of sub-range -> LDS; 8-cell fine key + histogram
    for (int pt = threadIdx.x; pt < n; pt += K2_THREADS) {
        float4 rec = records[base + pt];
        sx[pt] = rec.x; sy[pt] = rec.y; sz[pt] = rec.z;
        int fx = (cell_guess(rec.x) - cbx) >> 3;
        int fy = (cell_guess(rec.y) - cby) >> 3;
        int fz = (cell_guess(rec.z) - cbz) >> 3;
        fx = min(max(fx, 0), 3); fy = min(max(fy, 0), 3); fz = min(max(fz, 0), 3);
        int k = ((fx << 2) | fy) << 2 | fz;   // z fastest
        skeys[pt] = (unsigned char)k;
        atomicAdd(&hist[k], 1u);
    }
    __syncthreads();

    // phase 2: exclusive scan of 64 counts (first wave)
    if (threadIdx.x < 64) {
        unsigned v = hist[threadIdx.x];
        unsigned s = v;
        for (int off = 1; off < 64; off <<= 1) {
            unsigned t = __shfl_up(s, off, 64);
            if ((int)threadIdx.x >= off) s += t;
        }
        hist[threadIdx.x] = s - v;
    }
    __syncthreads();

    // phase 3: scatter point indices into fine-sorted order
    for (int pt = threadIdx.x; pt < n; pt += K2_THREADS) {
        unsigned slot = atomicAdd(&hist[skeys[pt]], 1u);
        order[slot] = (unsigned short)pt;
    }
    __syncthreads();

    // phase 4: process in z-sorted order; point data from LDS; z-pair gathers
    for (int pt = threadIdx.x; pt < n; pt += K2_THREADS) {
        int j = order[pt];
        sres[j] = interp_zpair(sx[j], sy[j], sz[j], values, sax);
    }
    __syncthreads();

    // phase 5: dense coalesced writeout
    for (int pt = threadIdx.x; pt < n; pt += K2_THREADS)
        res[base + pt] = sres[pt];
}

// ---------- K3: unscatter results to original order ----------

__global__ void unscatter(const int* __restrict__ inv,
                          const float* __restrict__ res,
                          float* __restrict__ out, int K) {
    int i = blockIdx.x * blockDim.x + threadIdx.x;
    if (i >= K) return;
    int s = inv[i];
    if (s >= 0) out[i] = res[s];
}

// ---------- fallback: direct (round-1) kernel ----------

__global__ void trilerp_direct(const float* __restrict__ x,
                               const float* __restrict__ values,
                               const float* __restrict__ px,
                               const float* __restrict__ py,
                               const float* __restrict__ pz,
                               float* __restrict__ out, int K) {
    int i = blockIdx.x * blockDim.x + threadIdx.x;
    if (i >= K) return;
    out[i] = interp_point_ax(x[3 * i], x[3 * i + 1], x[3 * i + 2],
                             values, px, py, pz);
}

extern "C" void kernel_launch(void* const* d_in, const int* in_sizes, int n_in,
                              void* d_out, int out_size, void* d_ws, size_t ws_size,
                              hipStream_t stream) {
    const float* x      = (const float*)d_in[0];
    const float* values = (const float*)d_in[1];
    const float* px     = (const float*)d_in[2];
    const float* py     = (const float*)d_in[3];
    const float* pz     = (const float*)d_in[4];
    float* out = (float*)d_out;

    int K = in_sizes[0] / 3;

    size_t cursor_bytes  = (size_t)NBINS * CURSOR_STRIDE * 4;   // 32 KB
    size_t records_bytes = (size_t)NBINS * CAP * 16;            // 50.3 MB
    size_t inv_bytes     = (size_t)K * 4;                       // 8 MB
    size_t res_bytes     = (size_t)NBINS * CAP * 4;             // 12.6 MB
    size_t need = cursor_bytes + records_bytes + inv_bytes + res_bytes;

    if (ws_size < need) {
        int grid = (K + 255) / 256;
        trilerp_direct<<<grid, 256, 0, stream>>>(x, values, px, py, pz, out, K);
        return;
    }

    char* p = (char*)d_ws;
    unsigned* cursor = (unsigned*)p;  p += cursor_bytes;
    float4* records  = (float4*)p;    p += records_bytes;
    int* inv         = (int*)p;       p += inv_bytes;
    float* res       = (float*)p;

    init_cursors<<<2, 256, 0, stream>>>(cursor);

    int nblk1 = (K + 4095) / 4096;
    bin_scatter2<<<nblk1, 1024, 0, stream>>>(x, K, cursor, records, inv,
                                             values, px, py, pz, out);

    interp_sub<<<NBINS * SUBS, K2_THREADS, 0, stream>>>(records, cursor,
                                                        values, px, py, pz, res);

    int nblk3 = (K + 255) / 256;
    unscatter<<<nblk3, 256, 0, stream>>>(inv, res, out, K);
}

// Round 9
// 85.630 us; speedup vs baseline: 1.7535x; 1.0414x over previous
//
#include <hip/hip_runtime.h>

#define GRIDN 256
#define BPA 8                     // coarse bins per axis (32 cells each)
#define NBINS (BPA * BPA * BPA)   // 512
#define CAP 6144                  // slots per coarse bin (interior mean 4741, sigma 69)
#define CURSOR_STRIDE 16          // one cursor per 64B line
#define FKEYS 512                 // fine keys: 8x8x8 sub-bins of 4x4x4 cells, z fastest

// ---------- shared helpers ----------

__device__ __forceinline__ int cell_guess(float c) {
    float t = (c + 0.64f) * 200.0f;
    int i = (int)t;
    return min(max(i, 0), GRIDN - 1);
}

// exact jnp.searchsorted(p, c, side='left') + clip semantics
__device__ __forceinline__ void dim_interp(float c, const float* __restrict__ p,
                                           int& il, int& ir, float& dl, float& dr) {
    const float SCALE = 0.005f;
    const float OFFSET = -0.64f;
    float t = (c - OFFSET) * (1.0f / SCALE);
    int i = (int)ceilf(t);
    i = min(max(i, 0), GRIDN - 1);
    while (i < GRIDN - 1 && p[i] < c) ++i;
    while (i > 0 && p[i - 1] >= c) --i;
    ir = i;
    il = max(i - 1, 0);
    dl = fmaxf(c - p[il], 0.0f);
    dr = fmaxf(p[ir] - c, 0.0f);
    if (dl == 0.0f && dr == 0.0f) { dl = 1.0f; dr = 1.0f; }
}

// full interp, 8 scalar gathers (rare fallback paths only)
__device__ __forceinline__ float interp_point_ax(float cx, float cy, float cz,
                                                 const float* __restrict__ values,
                                                 const float* __restrict__ ax,
                                                 const float* __restrict__ ay,
                                                 const float* __restrict__ az) {
    int ixl, ixr, iyl, iyr, izl, izr;
    float dxl, dxr, dyl, dyr, dzl, dzr;
    dim_interp(cx, ax, ixl, ixr, dxl, dxr);
    dim_interp(cy, ay, iyl, iyr, dyl, dyr);
    dim_interp(cz, az, izl, izr, dzl, dzr);
    int bxl = ixl << 16, bxr = ixr << 16;
    int byl = iyl << 8,  byr = iyr << 8;
    float num =
        values[bxl + byl + izl] * (dxr * dyr * dzr) +
        values[bxl + byl + izr] * (dxr * dyr * dzl) +
        values[bxl + byr + izl] * (dxr * dyl * dzr) +
        values[bxl + byr + izr] * (dxr * dyl * dzl) +
        values[bxr + byl + izl] * (dxl * dyr * dzr) +
        values[bxr + byl + izr] * (dxl * dyr * dzl) +
        values[bxr + byr + izl] * (dxl * dyl * dzr) +
        values[bxr + byr + izr] * (dxl * dyl * dzl);
    float den = (dxl + dxr) * (dyl + dyr) * (dzl + dzr);
    return num / den;
}

// interp with z-pair dwordx2 gathers (4 memory ops). ir in {il, il+1};
// izl <= 254 so the float2 is in-bounds; select .x when izr==izl.
__device__ __forceinline__ float interp_zpair(float cx, float cy, float cz,
                                              const float* __restrict__ values,
                                              const float* __restrict__ sax) {
    int ixl, ixr, iyl, iyr, izl, izr;
    float dxl, dxr, dyl, dyr, dzl, dzr;
    dim_interp(cx, sax,             ixl, ixr, dxl, dxr);
    dim_interp(cy, sax + GRIDN,     iyl, iyr, dyl, dyr);
    dim_interp(cz, sax + 2 * GRIDN, izl, izr, dzl, dzr);

    int bxl = ixl << 16, bxr = ixr << 16;
    int byl = iyl << 8,  byr = iyr << 8;

    float2 vll, vlr, vrl, vrr;
    __builtin_memcpy(&vll, &values[bxl + byl + izl], 8);
    __builtin_memcpy(&vlr, &values[bxl + byr + izl], 8);
    __builtin_memcpy(&vrl, &values[bxr + byl + izl], 8);
    __builtin_memcpy(&vrr, &values[bxr + byr + izl], 8);

    bool zsame = (izr == izl);
    float zll = vll.x, zlr = zsame ? vll.x : vll.y;
    float yll = vlr.x, ylr = zsame ? vlr.x : vlr.y;
    float xll = vrl.x, xlr = zsame ? vrl.x : vrl.y;
    float wll = vrr.x, wlr = zsame ? vrr.x : vrr.y;

    float num =
        (dxr * dyr) * (zll * dzr + zlr * dzl) +
        (dxr * dyl) * (yll * dzr + ylr * dzl) +
        (dxl * dyr) * (xll * dzr + xlr * dzl) +
        (dxl * dyl) * (wll * dzr + wlr * dzl);
    float den = (dxl + dxr) * (dyl + dyr) * (dzl + dzr);
    return num / den;
}

// ---------- K0: init padded cursors ----------

__global__ void init_cursors(unsigned* __restrict__ cursor) {
    int t = blockIdx.x * blockDim.x + threadIdx.x;
    if (t < NBINS) cursor[t * CURSOR_STRIDE] = (unsigned)(t * CAP);
}

// ---------- K1: block-aggregated coarse bin scatter (R3/R8-proven) ----------

__global__ __launch_bounds__(1024) void bin_scatter2(
        const float* __restrict__ x, int K,
        unsigned* __restrict__ cursor,
        float4* __restrict__ records,
        int* __restrict__ inv,
        const float* __restrict__ values,
        const float* __restrict__ px,
        const float* __restrict__ py,
        const float* __restrict__ pz,
        float* __restrict__ out) {
    __shared__ unsigned cnt[NBINS];
    __shared__ unsigned slotcur[NBINS];

    int base = blockIdx.x * 4096;
    int end = min(base + 4096, K);

    for (int t = threadIdx.x; t < NBINS; t += 1024) cnt[t] = 0;
    __syncthreads();

    for (int i = base + threadIdx.x; i < end; i += 1024) {
        int bx = cell_guess(x[3 * i]) >> 5;
        int by = cell_guess(x[3 * i + 1]) >> 5;
        int bz = cell_guess(x[3 * i + 2]) >> 5;
        atomicAdd(&cnt[(bx * BPA + by) * BPA + bz], 1u);
    }
    __syncthreads();

    for (int t = threadIdx.x; t < NBINS; t += 1024)
        slotcur[t] = cnt[t] ? atomicAdd(&cursor[t * CURSOR_STRIDE], cnt[t]) : 0u;
    __syncthreads();

    for (int i = base + threadIdx.x; i < end; i += 1024) {
        float cx = x[3 * i], cy = x[3 * i + 1], cz = x[3 * i + 2];
        int bx = cell_guess(cx) >> 5;
        int by = cell_guess(cy) >> 5;
        int bz = cell_guess(cz) >> 5;
        int b = (bx * BPA + by) * BPA + bz;
        unsigned s = atomicAdd(&slotcur[b], 1u);
        if (s < (unsigned)((b + 1) * CAP)) {
            records[s] = make_float4(cx, cy, cz, 0.0f);
            inv[i] = (int)s;
        } else {
            inv[i] = -1;   // overflow (statistically never): compute inline
            out[i] = interp_point_ax(cx, cy, cz, values, px, py, pz);
        }
    }
}

// ---------- K2: one 1024-thr block per coarse bin; full 512-key fine z-sort ----------

#define K2_THREADS 1024

__global__ __launch_bounds__(K2_THREADS) void interp_binsort(
        const float4* __restrict__ records,
        const unsigned* __restrict__ cursor,
        const float* __restrict__ values,
        const float* __restrict__ px,
        const float* __restrict__ py,
        const float* __restrict__ pz,
        float* __restrict__ res) {
    __shared__ float sax[3 * GRIDN];            // 3 KB
    __shared__ unsigned hist[FKEYS];            // 2 KB
    __shared__ unsigned short skeys[CAP];       // 12 KB
    __shared__ unsigned short order[CAP];       // 12 KB
    __shared__ float sx[CAP], sy[CAP], sz[CAP]; // 72 KB
    __shared__ float sres[CAP];                 // 24 KB   (total ~125 KB)

    // bijective XCD swizzle: consecutive bins (z-adjacent) on one XCD
    int nb = gridDim.x;               // 512, divisible by 8
    int b = blockIdx.x;
    int q = nb >> 3;
    int bin = (b & 7) * q + (b >> 3);

    for (int t = threadIdx.x; t < GRIDN; t += K2_THREADS) {
        sax[t] = px[t];
        sax[GRIDN + t] = py[t];
        sax[2 * GRIDN + t] = pz[t];
    }
    for (int t = threadIdx.x; t < FKEYS; t += K2_THREADS) hist[t] = 0;
    __syncthreads();

    unsigned binstart = (unsigned)bin * CAP;
    unsigned segend = min(cursor[bin * CURSOR_STRIDE], binstart + CAP);
    int npts = (int)(segend - binstart);
    if (npts <= 0) return;

    int cbx = (bin >> 6) << 5;
    int cby = ((bin >> 3) & 7) << 5;
    int cbz = (bin & 7) << 5;

    // phase 1: one coalesced read of the bin's records -> LDS; fine key + hist
    for (int pt = threadIdx.x; pt < npts; pt += K2_THREADS) {
        float4 rec = records[binstart + pt];
        sx[pt] = rec.x; sy[pt] = rec.y; sz[pt] = rec.z;
        int fx = (cell_guess(rec.x) - cbx) >> 2;
        int fy = (cell_guess(rec.y) - cby) >> 2;
        int fz = (cell_guess(rec.z) - cbz) >> 2;
        fx = min(max(fx, 0), 7); fy = min(max(fy, 0), 7); fz = min(max(fz, 0), 7);
        int k = ((fx << 3) | fy) << 3 | fz;   // z fastest -> sorted order is z-local
        skeys[pt] = (unsigned short)k;
        atomicAdd(&hist[k], 1u);
    }
    __syncthreads();

    // phase 2: exclusive scan of 512 counts (Hillis-Steele, uniform barriers)
    unsigned own = (threadIdx.x < FKEYS) ? hist[threadIdx.x] : 0u;
    for (int off = 1; off < FKEYS; off <<= 1) {
        unsigned v = 0;
        if (threadIdx.x < FKEYS && (int)threadIdx.x >= off) v = hist[threadIdx.x - off];
        __syncthreads();
        if (threadIdx.x < FKEYS) hist[threadIdx.x] += v;
        __syncthreads();
    }
    if (threadIdx.x < FKEYS) hist[threadIdx.x] -= own;   // inclusive -> exclusive
    __syncthreads();

    // phase 3: scatter point indices into fine-sorted order
    for (int pt = threadIdx.x; pt < npts; pt += K2_THREADS) {
        unsigned slot = atomicAdd(&hist[skeys[pt]], 1u);
        order[slot] = (unsigned short)pt;
    }
    __syncthreads();

    // phase 4: process in z-sorted order; a wave's 64 pts sit in ~7 adjacent
    // 4x4x4-cell sub-bins (one 4x4 column) -> heavy L1 line sharing
    for (int pt = threadIdx.x; pt < npts; pt += K2_THREADS) {
        int j = order[pt];
        sres[j] = interp_zpair(sx[j], sy[j], sz[j], values, sax);
    }
    __syncthreads();

    // phase 5: dense coalesced writeout
    for (int pt = threadIdx.x; pt < npts; pt += K2_THREADS)
        res[binstart + pt] = sres[pt];
}

// ---------- K3: unscatter results to original order ----------

__global__ void unscatter(const int* __restrict__ inv,
                          const float* __restrict__ res,
                          float* __restrict__ out, int K) {
    int i = blockIdx.x * blockDim.x + threadIdx.x;
    if (i >= K) return;
    int s = inv[i];
    if (s >= 0) out[i] = res[s];
}

// ---------- fallback: direct (round-1) kernel ----------

__global__ void trilerp_direct(const float* __restrict__ x,
                               const float* __restrict__ values,
                               const float* __restrict__ px,
                               const float* __restrict__ py,
                               const float* __restrict__ pz,
                               float* __restrict__ out, int K) {
    int i = blockIdx.x * blockDim.x + threadIdx.x;
    if (i >= K) return;
    out[i] = interp_point_ax(x[3 * i], x[3 * i + 1], x[3 * i + 2],
                             values, px, py, pz);
}

extern "C" void kernel_launch(void* const* d_in, const int* in_sizes, int n_in,
                              void* d_out, int out_size, void* d_ws, size_t ws_size,
                              hipStream_t stream) {
    const float* x      = (const float*)d_in[0];
    const float* values = (const float*)d_in[1];
    const float* px     = (const float*)d_in[2];
    const float* py     = (const float*)d_in[3];
    const float* pz     = (const float*)d_in[4];
    float* out = (float*)d_out;

    int K = in_sizes[0] / 3;

    size_t cursor_bytes  = (size_t)NBINS * CURSOR_STRIDE * 4;   // 32 KB
    size_t records_bytes = (size_t)NBINS * CAP * 16;            // 50.3 MB
    size_t inv_bytes     = (size_t)K * 4;                       // 8 MB
    size_t res_bytes     = (size_t)NBINS * CAP * 4;             // 12.6 MB
    size_t need = cursor_bytes + records_bytes + inv_bytes + res_bytes;

    if (ws_size < need) {
        int grid = (K + 255) / 256;
        trilerp_direct<<<grid, 256, 0, stream>>>(x, values, px, py, pz, out, K);
        return;
    }

    char* p = (char*)d_ws;
    unsigned* cursor = (unsigned*)p;  p += cursor_bytes;
    float4* records  = (float4*)p;    p += records_bytes;
    int* inv         = (int*)p;       p += inv_bytes;
    float* res       = (float*)p;

    init_cursors<<<2, 256, 0, stream>>>(cursor);

    int nblk1 = (K + 4095) / 4096;
    bin_scatter2<<<nblk1, 1024, 0, stream>>>(x, K, cursor, records, inv,
                                             values, px, py, pz, out);

    interp_binsort<<<NBINS, K2_THREADS, 0, stream>>>(records, cursor,
                                                     values, px, py, pz, res);

    int nblk3 = (K + 255) / 256;
    unscatter<<<nblk3, 256, 0, stream>>>(inv, res, out, K);
}